// Round 8
// baseline (150.568 us; speedup 1.0000x reference)
//
#include <hip/hip_runtime.h>
#include <hip/hip_bf16.h>

// GlassBlur via permutation composition.
// final_plane(p) = plane(P(p)),  P = tau_1 o ... o tau_N (first swap leftmost),
// so for chunks A (earlier, lower u) and B (later):  P(p) = A(B(p)).
// Pipeline: blur1 -> build (row perms, register window) -> tree (binary compose
// to span-32, 4-way ILP) -> compose_root (7 hops, ILP) -> blur2+apply fused
// (P in d_ws when it fits; fallback separate apply).
#define KW0 0.91921792f
#define KW1 0.04038762f
#define KW2 3.42560e-6f

#define HH 224
#define WW 224
#define NSW 49729          // 223*223
#define SLOT32 7616        // 34 rows x 224
#define LEAF_SLOT 676      // 3*224 + 4 pad
#define LEAF_BLK 21632     // 32*676 u16 per (b,j)
#define S32_IMG 53312      // 7*7616 u16 per image
#define P_STRIDE 50176     // root perm entries per image

// support rows for chunk covering swap-rows u in [u0, u0+nu)
__device__ __forceinline__ void node_meta(int u0, int nu, int& ys, int& nr) {
    ys = max(0, 223 - u0 - nu);
    int ye = min(223, 224 - u0);
    nr = ye - ys + 1;
}

// ---------------- blur1: f32 -> quantize u8 -> blur -> u8 plane ----------------
__global__ __launch_bounds__(256) void blur1_kernel(const float* __restrict__ x,
                                                    unsigned char* __restrict__ img) {
    const int rb = blockIdx.x, c = blockIdx.y, b = blockIdx.z;
    const int y0 = rb * 8;
    __shared__ float A[12][WW];
    __shared__ float Bv[8][WW];
    const float* xp = x + ((size_t)(b * 3 + c)) * HH * WW;

    for (int l = threadIdx.x; l < 12 * WW; l += 256) {
        int r = l / WW, xx = l - r * WW;
        int gy = min(max(y0 + r - 2, 0), HH - 1);
        float v = xp[gy * WW + xx];
        v = floorf(fminf(fmaxf(v * 255.0f, 0.0f), 255.0f));
        A[r][xx] = v;
    }
    __syncthreads();
    for (int l = threadIdx.x; l < 8 * WW; l += 256) {
        int r = l / WW, xx = l - r * WW;
        Bv[r][xx] = KW2 * A[r][xx] + KW1 * A[r + 1][xx] + KW0 * A[r + 2][xx]
                  + KW1 * A[r + 3][xx] + KW2 * A[r + 4][xx];
    }
    __syncthreads();
    unsigned char* op = img + ((size_t)(b * 3 + c)) * HH * WW;
    for (int l = threadIdx.x; l < 8 * WW; l += 256) {
        int r = l / WW, xx = l - r * WW;
        int c0 = max(xx - 2, 0), c1 = max(xx - 1, 0);
        int c3 = min(xx + 1, WW - 1), c4 = min(xx + 2, WW - 1);
        float s = KW2 * Bv[r][c0] + KW1 * Bv[r][c1] + KW0 * Bv[r][xx]
                + KW1 * Bv[r][c3] + KW2 * Bv[r][c4];
        op[(y0 + r) * WW + xx] = (unsigned char)floorf(s);
    }
}

// ---------------- build: pack idx -> register-window row perms -> leaves to global ----
// grid (7, 64), 256 threads. idx = pr*4 + pc (pr,pc in 0..2), identity pad = 5.
__global__ __launch_bounds__(256) void build_kernel(const int* __restrict__ deltas,
                                                    unsigned short* __restrict__ leafG) {
    const int j = blockIdx.x;
    const int b = blockIdx.y;
    const int U = j * 32;

    __shared__ __align__(16) unsigned short smA[LEAF_BLK];   // 43264 B
    __shared__ unsigned pk[32 * 29];                         //  3712 B

    const int tid = threadIdx.x;
    const int u = U + tid;

    // ---- pack: idx = clamp(dy)*4 + clamp(dx), 8 nibbles per u32 ----
    {
        const int2* Dbase = (const int2*)deltas + (size_t)b * NSW + (size_t)U * 223;
        for (int w = tid; w < 32 * 28; w += 256) {
            const int r = w / 28, k = w - r * 28;
            if (U + r < 223) {
                const int base = r * 223 + 8 * k;
                unsigned word = 0;
#pragma unroll
                for (int jj = 0; jj < 8; ++jj) {
                    const int i = 8 * k + jj;
                    unsigned idx = 5u;                       // identity pad (center)
                    if (i < 223) {
                        int2 d = Dbase[base + jj];
                        unsigned px = (unsigned)d.x, py = (unsigned)d.y;
                        if (U + r == 0) px = min(px, 1u);    // y=223 row clamp
                        if (i == 0) py = min(py, 1u);        // x=223 col clamp
                        idx = px * 4u + py;
                    }
                    word |= idx << (4 * jj);
                }
                pk[r * 29 + k] = word;
            }
        }
    }
    __syncthreads();

    // ---- serial register-window build (lane tid builds row u) ----
    if (tid < 32 && u < 223) {
        const int y = 223 - u;
        const int b0r = (y - 1) * 224, b1r = y * 224, b2r = (y + 1) * 224;
        unsigned short* Lf = &smA[tid * LEAF_SLOT];   // row-major [3][224] (+4 pad)
        const unsigned* pkr = &pk[tid * 29];

        unsigned w00 = b0r + 222, w01 = b0r + 223, w02 = b0r + 224;
        unsigned w10 = b1r + 222, w11 = b1r + 223, w12 = b1r + 224;
        unsigned w20 = b2r + 222, w21 = b2r + 223, w22 = b2r + 224;

        unsigned wA_ = pkr[0], wB_ = pkr[1], wC_ = pkr[2];

        // 2-level select tree: pr = idx>>2, pc = idx&3. Scatter codes:
        // row0:0,1,2  row1:4,(5=center),6  row2:8,9,10.
#define GB_STEP(KK, CA, CB, CC) {                                               \
            const int x_ = 223 - (ibase + (KK));                                \
            const unsigned wsel_ = (((KK) >> 3) == 0) ? wA_                     \
                                 : ((((KK) >> 3) == 1) ? wB_ : wC_);            \
            const unsigned idx_ = (wsel_ >> (4 * ((KK) & 7))) & 15u;            \
            const unsigned pr_ = idx_ >> 2, pc_ = idx_ & 3u;                    \
            const bool pc0_ = (pc_ == 0u), pc1_ = (pc_ == 1u);                  \
            const bool pr0_ = (pr_ == 0u), pr1_ = (pr_ == 1u);                  \
            const unsigned s0_ = pc0_ ? w0##CA : (pc1_ ? w0##CB : w0##CC);      \
            const unsigned s1_ = pc0_ ? w1##CA : (pc1_ ? w1##CB : w1##CC);      \
            const unsigned s2_ = pc0_ ? w2##CA : (pc1_ ? w2##CB : w2##CC);      \
            const unsigned v_ = pr0_ ? s0_ : (pr1_ ? s1_ : s2_);                \
            const unsigned c_ = w1##CB;                                         \
            w0##CA = idx_ == 0u  ? c_ : w0##CA;                                 \
            w0##CB = idx_ == 1u  ? c_ : w0##CB;                                 \
            w0##CC = idx_ == 2u  ? c_ : w0##CC;                                 \
            w1##CA = idx_ == 4u  ? c_ : w1##CA;                                 \
            w1##CC = idx_ == 6u  ? c_ : w1##CC;                                 \
            w2##CA = idx_ == 8u  ? c_ : w2##CA;                                 \
            w2##CB = idx_ == 9u  ? c_ : w2##CB;                                 \
            w2##CC = idx_ == 10u ? c_ : w2##CC;                                 \
            w1##CB = v_;                                                        \
            Lf[x_ + 1]   = (unsigned short)w0##CC;                              \
            Lf[x_ + 225] = (unsigned short)w1##CC;                              \
            Lf[x_ + 449] = (unsigned short)w2##CC;                              \
            w0##CC = (unsigned)(b0r + (x_ - 2));                                \
            w1##CC = (unsigned)(b1r + (x_ - 2));                                \
            w2##CC = (unsigned)(b2r + (x_ - 2));                                \
        }
#define GB_TRIPLE(K0) GB_STEP((K0), 0, 1, 2) GB_STEP((K0)+1, 2, 0, 1) GB_STEP((K0)+2, 1, 2, 0)
        // i=0 junk emissions (Lf[224],Lf[448],Lf[672]) are overwritten by the
        // final col-0/col-1 emits (672 is pad).
        for (int blk = 0; blk < 9; ++blk) {           // i = 0..215
            const int ibase = 24 * blk;
            const unsigned nA_ = pkr[min(3 * blk + 3, 27)];
            const unsigned nB_ = pkr[min(3 * blk + 4, 27)];
            const unsigned nC_ = pkr[min(3 * blk + 5, 27)];
            GB_TRIPLE(0)  GB_TRIPLE(3)  GB_TRIPLE(6)  GB_TRIPLE(9)
            GB_TRIPLE(12) GB_TRIPLE(15) GB_TRIPLE(18) GB_TRIPLE(21)
            wA_ = nA_; wB_ = nB_; wC_ = nC_;
        }
        {                                             // i = 216..222
            const int ibase = 216;
            GB_TRIPLE(0) GB_TRIPLE(3) GB_STEP(6, 0, 1, 2)
        }
        Lf[1] = (unsigned short)w01; Lf[225] = (unsigned short)w11; Lf[449] = (unsigned short)w21;
        Lf[0] = (unsigned short)w00; Lf[224] = (unsigned short)w10; Lf[448] = (unsigned short)w20;
#undef GB_TRIPLE
#undef GB_STEP
    }
    __syncthreads();

    // ---- copy leaves LDS -> global (coalesced uint4) ----
    unsigned short* g = leafG + (size_t)(b * 7 + j) * LEAF_BLK;
    for (int l = tid; l < LEAF_BLK / 8; l += 256)
        ((uint4*)g)[l] = ((const uint4*)smA)[l];
}

// ---- branch-free binary-tree level, flattened with 4-way ILP ----
template<int CSPAN, int CSLOT, int CCAP, int OSLOT>
__device__ __forceinline__ void level_flat(int NOUT,
                                           const unsigned short* __restrict__ child,
                                           unsigned short* __restrict__ outp,
                                           int U, int uEnd, int tid) {
    for (int jo = 0; jo < NOUT; ++jo) {
        const int u0 = U + jo * (2 * CSPAN);
        if (u0 >= uEnd) break;
        const int nu = min(2 * CSPAN, uEnd - u0);
        int ysO, nrO; node_meta(u0, nu, ysO, nrO);
        const int nuA = min(CSPAN, uEnd - u0);
        int ysA, nrA; node_meta(u0, nuA, ysA, nrA);
        const int nuB = min(CSPAN, uEnd - (u0 + CSPAN));
        int ysB = 0, nrB = 0;
        if (nuB > 0) node_meta(u0 + CSPAN, nuB, ysB, nrB);
        const unsigned short* Ap = child + (2 * jo) * CSLOT;
        const unsigned short* Bp = child + (2 * jo + 1) * CSLOT;
        unsigned short* R = outp + jo * OSLOT;
        const int cnt = nrO * 224;
        for (int e0 = tid; e0 < cnt; e0 += 1024) {
            int ee[4]; unsigned qq[4]; bool act[4];
#pragma unroll
            for (int t = 0; t < 4; ++t) {
                ee[t] = e0 + t * 256;
                act[t] = ee[t] < cnt;
                const int ec = act[t] ? ee[t] : 0;
                const int pr = ysO + ec / 224, pc = ec - (ec / 224) * 224;
                const int off = pr - ysB;
                const int offc = min(max(off, 0), CCAP);
                const unsigned r = Bp[offc * 224 + pc];
                qq[t] = ((unsigned)off < (unsigned)nrB) ? r : (unsigned)(pr * 224 + pc);
            }
#pragma unroll
            for (int t = 0; t < 4; ++t) {
                const unsigned qr = qq[t] / 224u;
                const int qc = (int)(qq[t] - qr * 224u);
                const int off = (int)qr - ysA;
                const int offc = min(max(off, 0), CCAP);
                const unsigned r = Ap[offc * 224 + qc];
                qq[t] = ((unsigned)off < (unsigned)nrA) ? r : qq[t];
            }
#pragma unroll
            for (int t = 0; t < 4; ++t)
                if (act[t]) R[ee[t]] = (unsigned short)qq[t];
        }
    }
}

// ---------------- tree: leaves (global) -> binary compose -> span-32 (global) ---------
// grid (7, 64), 256 threads.
__global__ __launch_bounds__(256) void tree_kernel(const unsigned short* __restrict__ leafG,
                                                   unsigned short* __restrict__ s32) {
    const int j = blockIdx.x;
    const int b = blockIdx.y;
    const int U = j * 32;
    const int uEnd = min(U + 32, 223);
    const int tid = threadIdx.x;

    __shared__ __align__(16) unsigned short smA[LEAF_BLK];   // 43264 B
    __shared__ unsigned short smB[14400];                    // 28800 B

    const unsigned short* g = leafG + (size_t)(b * 7 + j) * LEAF_BLK;
    for (int l = tid; l < LEAF_BLK / 8; l += 256)
        ((uint4*)smA)[l] = ((const uint4*)g)[l];
    __syncthreads();

    level_flat<1,  LEAF_SLOT, 2,  900>(16, smA, smB, U, uEnd, tid);  __syncthreads();
    level_flat<2,  900,       3, 1348>( 8, smB, smA, U, uEnd, tid);  __syncthreads();
    level_flat<4,  1348,      5, 2244>( 4, smA, smB, U, uEnd, tid);  __syncthreads();
    level_flat<8,  2244,      9, 4036>( 2, smB, smA, U, uEnd, tid);  __syncthreads();
    level_flat<16, 4036,     17, SLOT32>(1, smA,
                                         s32 + (size_t)b * S32_IMG + (size_t)j * SLOT32,
                                         U, uEnd, tid);
}

// ---------------- compose_root: 7 span-32 nodes -> root P (7 hops, 4-way ILP) ---------
// grid (64, 4), 512 threads.
__global__ __launch_bounds__(512) void compose_root_kernel(const unsigned short* __restrict__ in,
                                                           unsigned short* __restrict__ out) {
    const int b = blockIdx.x, sp = blockIdx.y;
    __shared__ unsigned short nd[7 * SLOT32];     // 106624 B
    const unsigned short* base = in + (size_t)b * S32_IMG;
    for (int l = threadIdx.x; l < (7 * SLOT32) / 8; l += 512)
        ((uint4*)nd)[l] = ((const uint4*)base)[l];
    __syncthreads();
    int ys[7], nr[7];
#pragma unroll
    for (int m = 0; m < 7; ++m) node_meta(32 * m, min(32, 223 - 32 * m), ys[m], nr[m]);
    unsigned short* R = out + (size_t)b * P_STRIDE;
    const int base0 = sp * 12544, base1 = base0 + 12544;
    for (int e0 = base0 + threadIdx.x; e0 < base1; e0 += 2048) {
        int ee[4]; unsigned q[4]; bool act[4];
#pragma unroll
        for (int t = 0; t < 4; ++t) {
            ee[t] = e0 + t * 512;
            act[t] = ee[t] < base1;
            q[t] = act[t] ? (unsigned)ee[t] : 0u;
        }
#pragma unroll
        for (int m = 6; m >= 0; --m) {
#pragma unroll
            for (int t = 0; t < 4; ++t) {
                const unsigned qr = q[t] / 224u;
                const int qc = (int)(q[t] - qr * 224u);
                const int off = (int)qr - ys[m];
                const int offc = min(max(off, 0), 33);
                const unsigned r = nd[m * SLOT32 + offc * 224 + qc];
                q[t] = ((unsigned)off < (unsigned)nr[m]) ? r : q[t];
            }
        }
#pragma unroll
        for (int t = 0; t < 4; ++t)
            if (act[t]) R[ee[t]] = (unsigned short)q[t];
    }
}

// ---------------- apply (fallback): plane(p) <- plane(P(p)), in-place via LDS ---------
__global__ __launch_bounds__(256) void apply_kernel(unsigned char* __restrict__ img,
                                                    const unsigned short* __restrict__ P) {
    const int plane = blockIdx.x;
    const int b = plane / 3;
    __shared__ __align__(16) unsigned char im[HH * WW];
    unsigned char* g = img + (size_t)plane * (HH * WW);
    for (int l = threadIdx.x; l < (HH * WW) / 16; l += 256)
        ((int4*)im)[l] = ((const int4*)g)[l];
    __syncthreads();
    const unsigned short* Pp = P + (size_t)b * P_STRIDE;
    for (int t = threadIdx.x; t < (HH * WW) / 8; t += 256) {
        uint4 pe = ((const uint4*)Pp)[t];
        unsigned e0 = pe.x & 0xffffu, e1 = pe.x >> 16;
        unsigned e2 = pe.y & 0xffffu, e3 = pe.y >> 16;
        unsigned e4 = pe.z & 0xffffu, e5 = pe.z >> 16;
        unsigned e6 = pe.w & 0xffffu, e7 = pe.w >> 16;
        unsigned lo = (unsigned)im[e0] | ((unsigned)im[e1] << 8)
                    | ((unsigned)im[e2] << 16) | ((unsigned)im[e3] << 24);
        unsigned hi = (unsigned)im[e4] | ((unsigned)im[e5] << 8)
                    | ((unsigned)im[e6] << 16) | ((unsigned)im[e7] << 24);
        ((uint2*)g)[t] = make_uint2(lo, hi);
    }
}

// ---------------- blur2 (plain, fallback) ----------------
__global__ __launch_bounds__(256) void blur2_kernel(const unsigned char* __restrict__ img,
                                                    float* __restrict__ out) {
    const int rb = blockIdx.x, c = blockIdx.y, b = blockIdx.z;
    const int y0 = rb * 8;
    __shared__ float A[12][WW];
    __shared__ float Bv[8][WW];
    const unsigned char* ip = img + ((size_t)(b * 3 + c)) * HH * WW;

    for (int l = threadIdx.x; l < 12 * WW; l += 256) {
        int r = l / WW, xx = l - r * WW;
        int gy = min(max(y0 + r - 2, 0), HH - 1);
        A[r][xx] = (float)ip[gy * WW + xx];
    }
    __syncthreads();
    for (int l = threadIdx.x; l < 8 * WW; l += 256) {
        int r = l / WW, xx = l - r * WW;
        Bv[r][xx] = KW2 * A[r][xx] + KW1 * A[r + 1][xx] + KW0 * A[r + 2][xx]
                  + KW1 * A[r + 3][xx] + KW2 * A[r + 4][xx];
    }
    __syncthreads();
    float* op = out + ((size_t)(b * 3 + c)) * HH * WW;
    for (int l = threadIdx.x; l < 8 * WW; l += 256) {
        int r = l / WW, xx = l - r * WW;
        int c0 = max(xx - 2, 0), c1 = max(xx - 1, 0);
        int c3 = min(xx + 1, WW - 1), c4 = min(xx + 2, WW - 1);
        float s = KW2 * Bv[r][c0] + KW1 * Bv[r][c1] + KW0 * Bv[r][xx]
                + KW1 * Bv[r][c3] + KW2 * Bv[r][c4];
        s = fminf(fmaxf(s, 0.0f), 255.0f);
        op[(y0 + r) * WW + xx] = floorf(s) / 255.0f;
    }
}

// ---------------- blur2_apply (fused): A[r][xx] = img[P[gy*224+xx]] ----------------
__global__ __launch_bounds__(256) void blur2_apply_kernel(const unsigned char* __restrict__ img,
                                                          const unsigned short* __restrict__ P,
                                                          float* __restrict__ out) {
    const int rb = blockIdx.x, c = blockIdx.y, b = blockIdx.z;
    const int y0 = rb * 8;
    __shared__ float A[12][WW];
    __shared__ float Bv[8][WW];
    const unsigned char* ip = img + ((size_t)(b * 3 + c)) * HH * WW;
    const unsigned short* Pp = P + (size_t)b * P_STRIDE;

    for (int l = threadIdx.x; l < 12 * WW; l += 256) {
        int r = l / WW, xx = l - r * WW;
        int gy = min(max(y0 + r - 2, 0), HH - 1);
        unsigned q = Pp[gy * WW + xx];        // coalesced u16 read
        A[r][xx] = (float)ip[q];              // near-local u8 gather (L2)
    }
    __syncthreads();
    for (int l = threadIdx.x; l < 8 * WW; l += 256) {
        int r = l / WW, xx = l - r * WW;
        Bv[r][xx] = KW2 * A[r][xx] + KW1 * A[r + 1][xx] + KW0 * A[r + 2][xx]
                  + KW1 * A[r + 3][xx] + KW2 * A[r + 4][xx];
    }
    __syncthreads();
    float* op = out + ((size_t)(b * 3 + c)) * HH * WW;
    for (int l = threadIdx.x; l < 8 * WW; l += 256) {
        int r = l / WW, xx = l - r * WW;
        int c0 = max(xx - 2, 0), c1 = max(xx - 1, 0);
        int c3 = min(xx + 1, WW - 1), c4 = min(xx + 2, WW - 1);
        float s = KW2 * Bv[r][c0] + KW1 * Bv[r][c1] + KW0 * Bv[r][xx]
                + KW1 * Bv[r][c3] + KW2 * Bv[r][c4];
        s = fminf(fmaxf(s, 0.0f), 255.0f);
        op[(y0 + r) * WW + xx] = floorf(s) / 255.0f;
    }
}

extern "C" void kernel_launch(void* const* d_in, const int* in_sizes, int n_in,
                              void* d_out, int out_size, void* d_ws, size_t ws_size,
                              hipStream_t stream) {
    const float* x      = (const float*)d_in[0];
    const int*   deltas = (const int*)d_in[1];
    float*       out    = (float*)d_out;
    unsigned char* img  = (unsigned char*)d_ws;                     // 9,633,792 B

    // scratch regions inside d_out (u16 view), all overwritten by final blur2 write:
    unsigned short* leafG = (unsigned short*)d_out;                 // 64*7*21632 u16 = 19.38 MB
    unsigned short* s32   = leafG + (size_t)64 * 7 * LEAF_BLK;      // 64*53312 u16  =  6.82 MB
    unsigned short* pFall = s32 + (size_t)64 * S32_IMG;             // 64*50176 u16  =  6.42 MB (ends 32.6/38.5 MB)

    const bool fused = ws_size >= (size_t)9633792 + (size_t)64 * P_STRIDE * 2;
    unsigned short* P = fused ? (unsigned short*)(img + 9633792) : pFall;

    dim3 gb(28, 3, 64);
    blur1_kernel<<<gb, 256, 0, stream>>>(x, img);

    build_kernel<<<dim3(7, 64), 256, 0, stream>>>(deltas, leafG);
    tree_kernel<<<dim3(7, 64), 256, 0, stream>>>(leafG, s32);
    compose_root_kernel<<<dim3(64, 4), 512, 0, stream>>>(s32, P);

    if (fused) {
        blur2_apply_kernel<<<gb, 256, 0, stream>>>(img, P, out);
    } else {
        apply_kernel<<<dim3(192), 256, 0, stream>>>(img, P);
        blur2_kernel<<<gb, 256, 0, stream>>>(img, out);
    }
}

// Round 9
// 140.430 us; speedup vs baseline: 1.0722x; 1.0722x over previous
//
#include <hip/hip_runtime.h>
#include <hip/hip_bf16.h>

// GlassBlur via permutation composition.
// final_plane(p) = plane(P(p)),  P = tau_1 o ... o tau_N (first swap leftmost),
// so for chunks A (earlier, lower u) and B (later):  P(p) = A(B(p)).
// Cell indices are 256-ENCODED (row<<8 | col) everywhere except the final root
// store (converted to row*224+col for apply/blur2).
// Pipeline: blur1 -> bc (pack + register-window row perms + 8-hop chase to
// span-8) -> tree32 (4-hop chase to span-32, sp-split high occupancy) ->
// root (7-hop chase -> P) -> blur2+apply fused (or apply+blur2 fallback).
#define KW0 0.91921792f
#define KW1 0.04038762f
#define KW2 3.42560e-6f

#define HH 224
#define WW 224
#define NSW 49729
#define SLOT8 2240          // 10 rows x 224
#define SLOT32 7616         // 34 rows x 224
#define S8_IMG 62720        // 28 * SLOT8
#define S32_IMG 53312       // 7 * SLOT32
#define P_STRIDE 50176
#define CH_STRIDE 2248      // span-8 LDS stage stride (16B-aligned)

// support rows for chunk covering swap-rows u in [u0, u0+nu)
__device__ __forceinline__ void node_meta(int u0, int nu, int& ys, int& nr) {
    ys = max(0, 223 - u0 - nu);
    int ye = min(223, 224 - u0);
    nr = ye - ys + 1;
}

// ---------------- blur1: f32 -> quantize u8 -> blur -> u8 plane ----------------
__global__ __launch_bounds__(256) void blur1_kernel(const float* __restrict__ x,
                                                    unsigned char* __restrict__ img) {
    const int rb = blockIdx.x, c = blockIdx.y, b = blockIdx.z;
    const int y0 = rb * 8;
    __shared__ float A[12][WW];
    __shared__ float Bv[8][WW];
    const float* xp = x + ((size_t)(b * 3 + c)) * HH * WW;

    for (int l = threadIdx.x; l < 12 * WW; l += 256) {
        int r = l / WW, xx = l - r * WW;
        int gy = min(max(y0 + r - 2, 0), HH - 1);
        float v = xp[gy * WW + xx];
        v = floorf(fminf(fmaxf(v * 255.0f, 0.0f), 255.0f));
        A[r][xx] = v;
    }
    __syncthreads();
    for (int l = threadIdx.x; l < 8 * WW; l += 256) {
        int r = l / WW, xx = l - r * WW;
        Bv[r][xx] = KW2 * A[r][xx] + KW1 * A[r + 1][xx] + KW0 * A[r + 2][xx]
                  + KW1 * A[r + 3][xx] + KW2 * A[r + 4][xx];
    }
    __syncthreads();
    unsigned char* op = img + ((size_t)(b * 3 + c)) * HH * WW;
    for (int l = threadIdx.x; l < 8 * WW; l += 256) {
        int r = l / WW, xx = l - r * WW;
        int c0 = max(xx - 2, 0), c1 = max(xx - 1, 0);
        int c3 = min(xx + 1, WW - 1), c4 = min(xx + 2, WW - 1);
        float s = KW2 * Bv[r][c0] + KW1 * Bv[r][c1] + KW0 * Bv[r][xx]
                + KW1 * Bv[r][c3] + KW2 * Bv[r][c4];
        op[(y0 + r) * WW + xx] = (unsigned char)floorf(s);
    }
}

// ---------------- bc: pack -> build 64 row-perms (wave0) -> 8-hop chase -> span-8 -----
// grid (4, 64), 256 threads. LDS: leaves 64x676 u16 (values 256-encoded) + pk.
__global__ __launch_bounds__(256) void bc_kernel(const int* __restrict__ deltas,
                                                 unsigned short* __restrict__ span8G) {
    const int j64 = blockIdx.x;          // 0..3
    const int b = blockIdx.y;
    const int U = j64 * 64;
    __shared__ unsigned short leafS[64 * 676];   // 86528 B
    __shared__ unsigned pk[64 * 29];             //  7424 B
    const int tid = threadIdx.x;

    // ---- pack: idx = clamp(dy)*4 + clamp(dx), 8 nibbles per u32 ----
    {
        const int2* Dbase = (const int2*)deltas + (size_t)b * NSW + (size_t)U * 223;
        for (int w = tid; w < 64 * 28; w += 256) {
            const int r = w / 28, k = w - r * 28;
            if (U + r < 223) {
                const int base = r * 223 + 8 * k;
                unsigned word = 0;
#pragma unroll
                for (int jj = 0; jj < 8; ++jj) {
                    const int i = 8 * k + jj;
                    unsigned idx = 5u;                       // identity pad (center)
                    if (i < 223) {
                        int2 d = Dbase[base + jj];
                        unsigned px = (unsigned)d.x, py = (unsigned)d.y;
                        if (U + r == 0) px = min(px, 1u);    // y=223 row clamp
                        if (i == 0) py = min(py, 1u);        // x=223 col clamp
                        idx = px * 4u + py;
                    }
                    word |= idx << (4 * jj);
                }
                pk[r * 29 + k] = word;
            }
        }
    }
    __syncthreads();

    // ---- build: lane tid (<64) builds row u = U+tid; 3x3 register window ----
    const int u = U + tid;
    if (tid < 64 && u < 223) {
        const int y = 223 - u;
        const unsigned b0r = (unsigned)(y - 1) << 8;
        const unsigned b1r = (unsigned)y << 8;
        const unsigned b2r = (unsigned)(y + 1) << 8;
        unsigned short* Lf = &leafS[tid * 676];   // [3][224] (+4 pad), values 256-enc
        const unsigned* pkr = &pk[tid * 29];

        unsigned w00 = b0r + 222, w01 = b0r + 223, w02 = b0r + 224;
        unsigned w10 = b1r + 222, w11 = b1r + 223, w12 = b1r + 224;
        unsigned w20 = b2r + 222, w21 = b2r + 223, w22 = b2r + 224;

        unsigned wA_ = pkr[0], wB_ = pkr[1], wC_ = pkr[2];

        // 2-level select: pr = idx>>2, pc = idx&3. Scatter codes:
        // row0:0,1,2  row1:4,(5=center),6  row2:8,9,10.
#define GB_STEP(KK, CA, CB, CC) {                                               \
            const int x_ = 223 - (ibase + (KK));                                \
            const unsigned wsel_ = (((KK) >> 3) == 0) ? wA_                     \
                                 : ((((KK) >> 3) == 1) ? wB_ : wC_);            \
            const unsigned idx_ = (wsel_ >> (4 * ((KK) & 7))) & 15u;            \
            const unsigned pr_ = idx_ >> 2, pc_ = idx_ & 3u;                    \
            const bool pc0_ = (pc_ == 0u), pc1_ = (pc_ == 1u);                  \
            const bool pr0_ = (pr_ == 0u), pr1_ = (pr_ == 1u);                  \
            const unsigned s0_ = pc0_ ? w0##CA : (pc1_ ? w0##CB : w0##CC);      \
            const unsigned s1_ = pc0_ ? w1##CA : (pc1_ ? w1##CB : w1##CC);      \
            const unsigned s2_ = pc0_ ? w2##CA : (pc1_ ? w2##CB : w2##CC);      \
            const unsigned v_ = pr0_ ? s0_ : (pr1_ ? s1_ : s2_);                \
            const unsigned c_ = w1##CB;                                         \
            w0##CA = idx_ == 0u  ? c_ : w0##CA;                                 \
            w0##CB = idx_ == 1u  ? c_ : w0##CB;                                 \
            w0##CC = idx_ == 2u  ? c_ : w0##CC;                                 \
            w1##CA = idx_ == 4u  ? c_ : w1##CA;                                 \
            w1##CC = idx_ == 6u  ? c_ : w1##CC;                                 \
            w2##CA = idx_ == 8u  ? c_ : w2##CA;                                 \
            w2##CB = idx_ == 9u  ? c_ : w2##CB;                                 \
            w2##CC = idx_ == 10u ? c_ : w2##CC;                                 \
            w1##CB = v_;                                                        \
            Lf[x_ + 1]   = (unsigned short)w0##CC;                              \
            Lf[x_ + 225] = (unsigned short)w1##CC;                              \
            Lf[x_ + 449] = (unsigned short)w2##CC;                              \
            w0##CC = b0r + (unsigned)(x_ - 2);                                  \
            w1##CC = b1r + (unsigned)(x_ - 2);                                  \
            w2##CC = b2r + (unsigned)(x_ - 2);                                  \
        }
#define GB_TRIPLE(K0) GB_STEP((K0), 0, 1, 2) GB_STEP((K0)+1, 2, 0, 1) GB_STEP((K0)+2, 1, 2, 0)
        // i=0 junk emissions (Lf[224],Lf[448],Lf[672]) are overwritten by the
        // final col-0/col-1 emits (672 is pad).
        for (int blk = 0; blk < 9; ++blk) {           // i = 0..215
            const int ibase = 24 * blk;
            const unsigned nA_ = pkr[min(3 * blk + 3, 27)];
            const unsigned nB_ = pkr[min(3 * blk + 4, 27)];
            const unsigned nC_ = pkr[min(3 * blk + 5, 27)];
            GB_TRIPLE(0)  GB_TRIPLE(3)  GB_TRIPLE(6)  GB_TRIPLE(9)
            GB_TRIPLE(12) GB_TRIPLE(15) GB_TRIPLE(18) GB_TRIPLE(21)
            wA_ = nA_; wB_ = nB_; wC_ = nC_;
        }
        {                                             // i = 216..222
            const int ibase = 216;
            GB_TRIPLE(0) GB_TRIPLE(3) GB_STEP(6, 0, 1, 2)
        }
        Lf[1] = (unsigned short)w01; Lf[225] = (unsigned short)w11; Lf[449] = (unsigned short)w21;
        Lf[0] = (unsigned short)w00; Lf[224] = (unsigned short)w10; Lf[448] = (unsigned short)w20;
#undef GB_TRIPLE
#undef GB_STEP
    }
    __syncthreads();

    // ---- chase: 8-hop (latest->earliest leaf) -> span-8 nodes, 5-ILP rows ----
    const int col = tid;
    if (col < 224) {
        for (int kk = 0; kk < 8; ++kk) {
            const int u0 = U + 8 * kk;
            if (u0 >= 223) break;
            const int nu = min(8, 223 - u0);
            int ysO, nrO; node_meta(u0, nu, ysO, nrO);
            unsigned short* R = span8G + ((size_t)b * 28 + (size_t)(u0 >> 3)) * SLOT8;
            for (int r0 = 0; r0 < nrO; r0 += 5) {
                unsigned q[5]; bool act[5];
#pragma unroll
                for (int t = 0; t < 5; ++t) {
                    const int rr = r0 + t;
                    act[t] = rr < nrO;
                    const int pr = ysO + min(rr, nrO - 1);
                    q[t] = ((unsigned)pr << 8) | (unsigned)col;
                }
                for (int m = nu - 1; m >= 0; --m) {
                    const int ysL = 222 - (u0 + m);
                    const int lbase = (8 * kk + m) * 676;
#pragma unroll
                    for (int t = 0; t < 5; ++t) {
                        const unsigned qr = q[t] >> 8;
                        const int qc = (int)(q[t] & 255u);
                        const int off = (int)qr - ysL;
                        const int offc = min(max(off, 0), 2);
                        const unsigned rv = leafS[lbase + __mul24(offc, 224) + qc];
                        q[t] = ((unsigned)off < 3u) ? rv : q[t];
                    }
                }
#pragma unroll
                for (int t = 0; t < 5; ++t)
                    if (act[t]) R[(r0 + t) * 224 + col] = (unsigned short)q[t];
            }
        }
    }
}

// ---------------- tree32: 4 span-8 nodes -> span-32 (4-hop chase, sp-split) -----------
// grid (7, 64, 4), 256 threads, 18KB LDS -> high occupancy.
__global__ __launch_bounds__(256) void tree32_kernel(const unsigned short* __restrict__ span8G,
                                                     unsigned short* __restrict__ span32G) {
    const int j = blockIdx.x, b = blockIdx.y, sp = blockIdx.z;
    __shared__ unsigned short ch[4 * CH_STRIDE];   // 17984 B
    const int tid = threadIdx.x;
#pragma unroll
    for (int m = 0; m < 4; ++m) {
        const uint4* src = (const uint4*)(span8G + ((size_t)b * 28 + (size_t)(4 * j + m)) * SLOT8);
        uint4* dst = (uint4*)(&ch[m * CH_STRIDE]);
        for (int l = tid; l < SLOT8 / 8; l += 256) dst[l] = src[l];
    }
    __syncthreads();
    int ysm[4], nrm[4];
#pragma unroll
    for (int m = 0; m < 4; ++m) {
        const int u0m = 32 * j + 8 * m;
        node_meta(u0m, min(8, 223 - u0m), ysm[m], nrm[m]);
    }
    int ysO, nrO; node_meta(32 * j, min(32, 223 - 32 * j), ysO, nrO);
    const int col = tid;
    if (col < 224) {
        const int rBeg = sp * 9, rEnd = min(rBeg + 9, nrO);
        unsigned short* R = span32G + ((size_t)b * 7 + j) * SLOT32;
        for (int r0 = rBeg; r0 < rEnd; r0 += 5) {
            unsigned q[5]; bool act[5];
#pragma unroll
            for (int t = 0; t < 5; ++t) {
                const int rr = r0 + t;
                act[t] = rr < rEnd;
                const int pr = ysO + min(rr, rEnd - 1);
                q[t] = ((unsigned)pr << 8) | (unsigned)col;
            }
#pragma unroll
            for (int m = 3; m >= 0; --m) {
#pragma unroll
                for (int t = 0; t < 5; ++t) {
                    const unsigned qr = q[t] >> 8;
                    const int qc = (int)(q[t] & 255u);
                    const int off = (int)qr - ysm[m];
                    const int offc = min(max(off, 0), 9);
                    const unsigned rv = ch[m * CH_STRIDE + __mul24(offc, 224) + qc];
                    q[t] = ((unsigned)off < (unsigned)nrm[m]) ? rv : q[t];
                }
            }
#pragma unroll
            for (int t = 0; t < 5; ++t)
                if (act[t]) R[(r0 + t) * 224 + col] = (unsigned short)q[t];
        }
    }
}

// ---------------- root: 7 span-32 nodes -> P (7-hop chase, 4-ILP, convert 224) --------
// grid (64, 4), 512 threads.
__global__ __launch_bounds__(512) void root_kernel(const unsigned short* __restrict__ span32G,
                                                   unsigned short* __restrict__ P) {
    const int b = blockIdx.x, sp = blockIdx.y;
    __shared__ unsigned short nd[7 * SLOT32];     // 106624 B
    const uint4* src = (const uint4*)(span32G + (size_t)b * S32_IMG);
    for (int l = threadIdx.x; l < S32_IMG / 8; l += 512)
        ((uint4*)nd)[l] = src[l];
    __syncthreads();
    int ys[7], nr[7];
#pragma unroll
    for (int m = 0; m < 7; ++m) node_meta(32 * m, min(32, 223 - 32 * m), ys[m], nr[m]);
    const int row0 = threadIdx.x / 224;           // 0,1 active; >=2 idle
    const int col = threadIdx.x - row0 * 224;
    if (row0 < 2) {
        unsigned short* Pb = P + (size_t)b * P_STRIDE;
        for (int g = 0; g < 7; ++g) {
            unsigned q[4]; int prv[4];
#pragma unroll
            for (int t = 0; t < 4; ++t) {
                prv[t] = sp * 56 + row0 + 2 * (4 * g + t);
                q[t] = ((unsigned)prv[t] << 8) | (unsigned)col;
            }
#pragma unroll
            for (int m = 6; m >= 0; --m) {
#pragma unroll
                for (int t = 0; t < 4; ++t) {
                    const unsigned qr = q[t] >> 8;
                    const int qc = (int)(q[t] & 255u);
                    const int off = (int)qr - ys[m];
                    const int offc = min(max(off, 0), 33);
                    const unsigned rv = nd[m * SLOT32 + __mul24(offc, 224) + qc];
                    q[t] = ((unsigned)off < (unsigned)nr[m]) ? rv : q[t];
                }
            }
#pragma unroll
            for (int t = 0; t < 4; ++t)
                Pb[prv[t] * 224 + col] =
                    (unsigned short)(__mul24((int)(q[t] >> 8), 224) + (int)(q[t] & 255u));
        }
    }
}

// ---------------- apply (fallback): plane(p) <- plane(P(p)), in-place via LDS ---------
__global__ __launch_bounds__(256) void apply_kernel(unsigned char* __restrict__ img,
                                                    const unsigned short* __restrict__ P) {
    const int plane = blockIdx.x;
    const int b = plane / 3;
    __shared__ __align__(16) unsigned char im[HH * WW];
    unsigned char* g = img + (size_t)plane * (HH * WW);
    for (int l = threadIdx.x; l < (HH * WW) / 16; l += 256)
        ((int4*)im)[l] = ((const int4*)g)[l];
    __syncthreads();
    const unsigned short* Pp = P + (size_t)b * P_STRIDE;
    for (int t = threadIdx.x; t < (HH * WW) / 8; t += 256) {
        uint4 pe = ((const uint4*)Pp)[t];
        unsigned e0 = pe.x & 0xffffu, e1 = pe.x >> 16;
        unsigned e2 = pe.y & 0xffffu, e3 = pe.y >> 16;
        unsigned e4 = pe.z & 0xffffu, e5 = pe.z >> 16;
        unsigned e6 = pe.w & 0xffffu, e7 = pe.w >> 16;
        unsigned lo = (unsigned)im[e0] | ((unsigned)im[e1] << 8)
                    | ((unsigned)im[e2] << 16) | ((unsigned)im[e3] << 24);
        unsigned hi = (unsigned)im[e4] | ((unsigned)im[e5] << 8)
                    | ((unsigned)im[e6] << 16) | ((unsigned)im[e7] << 24);
        ((uint2*)g)[t] = make_uint2(lo, hi);
    }
}

// ---------------- blur2 (plain, fallback) ----------------
__global__ __launch_bounds__(256) void blur2_kernel(const unsigned char* __restrict__ img,
                                                    float* __restrict__ out) {
    const int rb = blockIdx.x, c = blockIdx.y, b = blockIdx.z;
    const int y0 = rb * 8;
    __shared__ float A[12][WW];
    __shared__ float Bv[8][WW];
    const unsigned char* ip = img + ((size_t)(b * 3 + c)) * HH * WW;

    for (int l = threadIdx.x; l < 12 * WW; l += 256) {
        int r = l / WW, xx = l - r * WW;
        int gy = min(max(y0 + r - 2, 0), HH - 1);
        A[r][xx] = (float)ip[gy * WW + xx];
    }
    __syncthreads();
    for (int l = threadIdx.x; l < 8 * WW; l += 256) {
        int r = l / WW, xx = l - r * WW;
        Bv[r][xx] = KW2 * A[r][xx] + KW1 * A[r + 1][xx] + KW0 * A[r + 2][xx]
                  + KW1 * A[r + 3][xx] + KW2 * A[r + 4][xx];
    }
    __syncthreads();
    float* op = out + ((size_t)(b * 3 + c)) * HH * WW;
    for (int l = threadIdx.x; l < 8 * WW; l += 256) {
        int r = l / WW, xx = l - r * WW;
        int c0 = max(xx - 2, 0), c1 = max(xx - 1, 0);
        int c3 = min(xx + 1, WW - 1), c4 = min(xx + 2, WW - 1);
        float s = KW2 * Bv[r][c0] + KW1 * Bv[r][c1] + KW0 * Bv[r][xx]
                + KW1 * Bv[r][c3] + KW2 * Bv[r][c4];
        s = fminf(fmaxf(s, 0.0f), 255.0f);
        op[(y0 + r) * WW + xx] = floorf(s) / 255.0f;
    }
}

// ---------------- blur2_apply (fused): A[r][xx] = img[P[gy*224+xx]] ----------------
__global__ __launch_bounds__(256) void blur2_apply_kernel(const unsigned char* __restrict__ img,
                                                          const unsigned short* __restrict__ P,
                                                          float* __restrict__ out) {
    const int rb = blockIdx.x, c = blockIdx.y, b = blockIdx.z;
    const int y0 = rb * 8;
    __shared__ float A[12][WW];
    __shared__ float Bv[8][WW];
    const unsigned char* ip = img + ((size_t)(b * 3 + c)) * HH * WW;
    const unsigned short* Pp = P + (size_t)b * P_STRIDE;

    for (int l = threadIdx.x; l < 12 * WW; l += 256) {
        int r = l / WW, xx = l - r * WW;
        int gy = min(max(y0 + r - 2, 0), HH - 1);
        unsigned q = Pp[gy * WW + xx];
        A[r][xx] = (float)ip[q];
    }
    __syncthreads();
    for (int l = threadIdx.x; l < 8 * WW; l += 256) {
        int r = l / WW, xx = l - r * WW;
        Bv[r][xx] = KW2 * A[r][xx] + KW1 * A[r + 1][xx] + KW0 * A[r + 2][xx]
                  + KW1 * A[r + 3][xx] + KW2 * A[r + 4][xx];
    }
    __syncthreads();
    float* op = out + ((size_t)(b * 3 + c)) * HH * WW;
    for (int l = threadIdx.x; l < 8 * WW; l += 256) {
        int r = l / WW, xx = l - r * WW;
        int c0 = max(xx - 2, 0), c1 = max(xx - 1, 0);
        int c3 = min(xx + 1, WW - 1), c4 = min(xx + 2, WW - 1);
        float s = KW2 * Bv[r][c0] + KW1 * Bv[r][c1] + KW0 * Bv[r][xx]
                + KW1 * Bv[r][c3] + KW2 * Bv[r][c4];
        s = fminf(fmaxf(s, 0.0f), 255.0f);
        op[(y0 + r) * WW + xx] = floorf(s) / 255.0f;
    }
}

extern "C" void kernel_launch(void* const* d_in, const int* in_sizes, int n_in,
                              void* d_out, int out_size, void* d_ws, size_t ws_size,
                              hipStream_t stream) {
    const float* x      = (const float*)d_in[0];
    const int*   deltas = (const int*)d_in[1];
    float*       out    = (float*)d_out;
    unsigned char* img  = (unsigned char*)d_ws;                     // 9,633,792 B

    // scratch in d_out (u16 view), all dead before the final out write:
    unsigned short* span8G  = (unsigned short*)d_out;               // 64*62720 u16 = 8.03 MB
    unsigned short* span32G = span8G + (size_t)64 * S8_IMG;         // 64*53312 u16 = 6.82 MB
    unsigned short* pFall   = span32G + (size_t)64 * S32_IMG;       // 64*50176 u16 = 6.42 MB (ends 21.3/38.5 MB)

    const bool fused = ws_size >= (size_t)9633792 + (size_t)64 * P_STRIDE * 2;
    unsigned short* P = fused ? (unsigned short*)(img + 9633792) : pFall;

    dim3 gb(28, 3, 64);
    blur1_kernel<<<gb, 256, 0, stream>>>(x, img);

    bc_kernel<<<dim3(4, 64), 256, 0, stream>>>(deltas, span8G);
    tree32_kernel<<<dim3(7, 64, 4), 256, 0, stream>>>(span8G, span32G);
    root_kernel<<<dim3(64, 4), 512, 0, stream>>>(span32G, P);

    if (fused) {
        blur2_apply_kernel<<<gb, 256, 0, stream>>>(img, P, out);
    } else {
        apply_kernel<<<dim3(192), 256, 0, stream>>>(img, P);
        blur2_kernel<<<gb, 256, 0, stream>>>(img, out);
    }
}

// Round 10
// 131.583 us; speedup vs baseline: 1.1443x; 1.0672x over previous
//
#include <hip/hip_runtime.h>
#include <hip/hip_bf16.h>

// GlassBlur via permutation composition.
// final_plane(p) = plane(P(p)),  P = tau_1 o ... o tau_N (first swap leftmost),
// so for chunks A (earlier, lower u) and B (later):  P(p) = A(B(p)) -> apply
// later chunks first when chasing (m descending).
// Cell indices are 256-ENCODED (row<<8 | col) until the root store.
// Pipeline: blur1 -> build (row perms, 47KB, 3 blk/CU) -> chase8 (8-hop,
// 10.8KB, 7 blk/CU) -> chase64 (8-hop, 35.8KB, 4 blk/CU) -> root4 (4-hop,
// 118KB) -> blur2+apply fused (P in d_ws when it fits; fallback separate).
#define KW0 0.91921792f
#define KW1 0.04038762f
#define KW2 3.42560e-6f

#define HH 224
#define WW 224
#define NSW 49729
#define SLOT8 2240          // 10 rows x 224
#define SLOT64 14784        // 66 rows x 224
#define LEAF_GRP 5408       // 8 leaves x 676 (u16) per span-8 group
#define P_STRIDE 50176

// support rows for chunk covering swap-rows u in [u0, u0+nu)
__device__ __forceinline__ void node_meta(int u0, int nu, int& ys, int& nr) {
    ys = max(0, 223 - u0 - nu);
    int ye = min(223, 224 - u0);
    nr = ye - ys + 1;
}

// ---------------- blur1: f32 -> quantize u8 -> blur -> u8 plane ----------------
__global__ __launch_bounds__(256) void blur1_kernel(const float* __restrict__ x,
                                                    unsigned char* __restrict__ img) {
    const int rb = blockIdx.x, c = blockIdx.y, b = blockIdx.z;
    const int y0 = rb * 8;
    __shared__ float A[12][WW];
    __shared__ float Bv[8][WW];
    const float* xp = x + ((size_t)(b * 3 + c)) * HH * WW;

    for (int l = threadIdx.x; l < 12 * WW; l += 256) {
        int r = l / WW, xx = l - r * WW;
        int gy = min(max(y0 + r - 2, 0), HH - 1);
        float v = xp[gy * WW + xx];
        v = floorf(fminf(fmaxf(v * 255.0f, 0.0f), 255.0f));
        A[r][xx] = v;
    }
    __syncthreads();
    for (int l = threadIdx.x; l < 8 * WW; l += 256) {
        int r = l / WW, xx = l - r * WW;
        Bv[r][xx] = KW2 * A[r][xx] + KW1 * A[r + 1][xx] + KW0 * A[r + 2][xx]
                  + KW1 * A[r + 3][xx] + KW2 * A[r + 4][xx];
    }
    __syncthreads();
    unsigned char* op = img + ((size_t)(b * 3 + c)) * HH * WW;
    for (int l = threadIdx.x; l < 8 * WW; l += 256) {
        int r = l / WW, xx = l - r * WW;
        int c0 = max(xx - 2, 0), c1 = max(xx - 1, 0);
        int c3 = min(xx + 1, WW - 1), c4 = min(xx + 2, WW - 1);
        float s = KW2 * Bv[r][c0] + KW1 * Bv[r][c1] + KW0 * Bv[r][xx]
                + KW1 * Bv[r][c3] + KW2 * Bv[r][c4];
        op[(y0 + r) * WW + xx] = (unsigned char)floorf(s);
    }
}

// ---------------- build: pack idx -> register-window row perms -> leaves (256-enc) ----
// grid (7, 64), 256 threads, 47KB LDS -> 3 blocks/CU.
__global__ __launch_bounds__(256) void build_kernel(const int* __restrict__ deltas,
                                                    unsigned short* __restrict__ leafG) {
    const int j = blockIdx.x;
    const int b = blockIdx.y;
    const int U = j * 32;

    __shared__ __align__(16) unsigned short smA[32 * 676];   // 43264 B
    __shared__ unsigned pk[32 * 29];                         //  3712 B

    const int tid = threadIdx.x;
    const int u = U + tid;

    // ---- pack: idx = clamp(dy)*4 + clamp(dx), 8 nibbles per u32 ----
    {
        const int2* Dbase = (const int2*)deltas + (size_t)b * NSW + (size_t)U * 223;
        for (int w = tid; w < 32 * 28; w += 256) {
            const int r = w / 28, k = w - r * 28;
            if (U + r < 223) {
                const int base = r * 223 + 8 * k;
                unsigned word = 0;
#pragma unroll
                for (int jj = 0; jj < 8; ++jj) {
                    const int i = 8 * k + jj;
                    unsigned idx = 5u;                       // identity pad (center)
                    if (i < 223) {
                        int2 d = Dbase[base + jj];
                        unsigned px = (unsigned)d.x, py = (unsigned)d.y;
                        if (U + r == 0) px = min(px, 1u);    // y=223 row clamp
                        if (i == 0) py = min(py, 1u);        // x=223 col clamp
                        idx = px * 4u + py;
                    }
                    word |= idx << (4 * jj);
                }
                pk[r * 29 + k] = word;
            }
        }
    }
    __syncthreads();

    // ---- serial register-window build (lane tid builds row u); values 256-enc ----
    if (tid < 32 && u < 223) {
        const int y = 223 - u;
        const unsigned b0r = (unsigned)(y - 1) << 8;
        const unsigned b1r = (unsigned)y << 8;
        const unsigned b2r = (unsigned)(y + 1) << 8;
        unsigned short* Lf = &smA[tid * 676];   // row-major [3][224] (+4 pad)
        const unsigned* pkr = &pk[tid * 29];

        unsigned w00 = b0r + 222, w01 = b0r + 223, w02 = b0r + 224;
        unsigned w10 = b1r + 222, w11 = b1r + 223, w12 = b1r + 224;
        unsigned w20 = b2r + 222, w21 = b2r + 223, w22 = b2r + 224;

        unsigned wA_ = pkr[0], wB_ = pkr[1], wC_ = pkr[2];

        // 2-level select: pr = idx>>2, pc = idx&3. Scatter codes:
        // row0:0,1,2  row1:4,(5=center),6  row2:8,9,10.
#define GB_STEP(KK, CA, CB, CC) {                                               \
            const int x_ = 223 - (ibase + (KK));                                \
            const unsigned wsel_ = (((KK) >> 3) == 0) ? wA_                     \
                                 : ((((KK) >> 3) == 1) ? wB_ : wC_);            \
            const unsigned idx_ = (wsel_ >> (4 * ((KK) & 7))) & 15u;            \
            const unsigned pr_ = idx_ >> 2, pc_ = idx_ & 3u;                    \
            const bool pc0_ = (pc_ == 0u), pc1_ = (pc_ == 1u);                  \
            const bool pr0_ = (pr_ == 0u), pr1_ = (pr_ == 1u);                  \
            const unsigned s0_ = pc0_ ? w0##CA : (pc1_ ? w0##CB : w0##CC);      \
            const unsigned s1_ = pc0_ ? w1##CA : (pc1_ ? w1##CB : w1##CC);      \
            const unsigned s2_ = pc0_ ? w2##CA : (pc1_ ? w2##CB : w2##CC);      \
            const unsigned v_ = pr0_ ? s0_ : (pr1_ ? s1_ : s2_);                \
            const unsigned c_ = w1##CB;                                         \
            w0##CA = idx_ == 0u  ? c_ : w0##CA;                                 \
            w0##CB = idx_ == 1u  ? c_ : w0##CB;                                 \
            w0##CC = idx_ == 2u  ? c_ : w0##CC;                                 \
            w1##CA = idx_ == 4u  ? c_ : w1##CA;                                 \
            w1##CC = idx_ == 6u  ? c_ : w1##CC;                                 \
            w2##CA = idx_ == 8u  ? c_ : w2##CA;                                 \
            w2##CB = idx_ == 9u  ? c_ : w2##CB;                                 \
            w2##CC = idx_ == 10u ? c_ : w2##CC;                                 \
            w1##CB = v_;                                                        \
            Lf[x_ + 1]   = (unsigned short)w0##CC;                              \
            Lf[x_ + 225] = (unsigned short)w1##CC;                              \
            Lf[x_ + 449] = (unsigned short)w2##CC;                              \
            w0##CC = b0r + (unsigned)(x_ - 2);                                  \
            w1##CC = b1r + (unsigned)(x_ - 2);                                  \
            w2##CC = b2r + (unsigned)(x_ - 2);                                  \
        }
#define GB_TRIPLE(K0) GB_STEP((K0), 0, 1, 2) GB_STEP((K0)+1, 2, 0, 1) GB_STEP((K0)+2, 1, 2, 0)
        // i=0 junk emissions (Lf[224],Lf[448],Lf[672]) are overwritten by the
        // final col-0/col-1 emits (672 is pad).
        for (int blk = 0; blk < 9; ++blk) {           // i = 0..215
            const int ibase = 24 * blk;
            const unsigned nA_ = pkr[min(3 * blk + 3, 27)];
            const unsigned nB_ = pkr[min(3 * blk + 4, 27)];
            const unsigned nC_ = pkr[min(3 * blk + 5, 27)];
            GB_TRIPLE(0)  GB_TRIPLE(3)  GB_TRIPLE(6)  GB_TRIPLE(9)
            GB_TRIPLE(12) GB_TRIPLE(15) GB_TRIPLE(18) GB_TRIPLE(21)
            wA_ = nA_; wB_ = nB_; wC_ = nC_;
        }
        {                                             // i = 216..222
            const int ibase = 216;
            GB_TRIPLE(0) GB_TRIPLE(3) GB_STEP(6, 0, 1, 2)
        }
        Lf[1] = (unsigned short)w01; Lf[225] = (unsigned short)w11; Lf[449] = (unsigned short)w21;
        Lf[0] = (unsigned short)w00; Lf[224] = (unsigned short)w10; Lf[448] = (unsigned short)w20;
#undef GB_TRIPLE
#undef GB_STEP
    }
    __syncthreads();

    // ---- copy 32 leaves (= 4 span-8 groups) LDS -> global, coalesced ----
    unsigned short* g = leafG + ((size_t)b * 28 + (size_t)(4 * j)) * LEAF_GRP;
    for (int l = tid; l < (32 * 676) / 8; l += 256)
        ((uint4*)g)[l] = ((const uint4*)smA)[l];
}

// ---------------- chase8: 8 leaves -> span-8 node (8 hops, 9-chain ILP) ----------------
// grid (28, 64), 256 threads, 10.8KB LDS -> 7 blocks/CU resident.
__global__ __launch_bounds__(256) void chase8_kernel(const unsigned short* __restrict__ leafG,
                                                     unsigned short* __restrict__ span8G) {
    const int j8 = blockIdx.x, b = blockIdx.y;
    __shared__ unsigned short lf[8 * 676];   // 10816 B
    const int tid = threadIdx.x;
    const unsigned short* src = leafG + ((size_t)b * 28 + j8) * LEAF_GRP;
    for (int l = tid; l < LEAF_GRP / 8; l += 256)
        ((uint4*)lf)[l] = ((const uint4*)src)[l];
    __syncthreads();

    const int u0 = j8 * 8;
    const int nu = min(8, 223 - u0);
    int ysO, nrO; node_meta(u0, nu, ysO, nrO);
    const int cnt = nrO * 224;

    unsigned q[9]; bool act[9];
#pragma unroll
    for (int t = 0; t < 9; ++t) {
        const int e = tid + t * 256;
        act[t] = e < cnt;
        const int ec = act[t] ? e : 0;
        const int pr = ysO + ec / 224, pc = ec - (ec / 224) * 224;
        q[t] = ((unsigned)pr << 8) | (unsigned)pc;
    }
    for (int m = nu - 1; m >= 0; --m) {           // later leaves first
        const int ysL = 222 - (u0 + m);
        const unsigned short* lb = lf + m * 676;
#pragma unroll
        for (int t = 0; t < 9; ++t) {
            const unsigned qr = q[t] >> 8;
            const int qc = (int)(q[t] & 255u);
            const int off = (int)qr - ysL;
            const int offc = min(max(off, 0), 2);
            const unsigned rv = lb[__mul24(offc, 224) + qc];
            q[t] = ((unsigned)off < 3u) ? rv : q[t];
        }
    }
    unsigned short* R = span8G + ((size_t)b * 28 + j8) * SLOT8;
#pragma unroll
    for (int t = 0; t < 9; ++t)
        if (act[t]) R[tid + t * 256] = (unsigned short)q[t];
}

// ---------------- chase64: 8 span-8 nodes -> span-64 node (8 hops, sp-split) -----------
// grid (4, 64, 4), 256 threads, 35.8KB LDS -> 4 blocks/CU, all 1024 resident.
__global__ __launch_bounds__(256) void chase64_kernel(const unsigned short* __restrict__ span8G,
                                                      unsigned short* __restrict__ span64G) {
    const int g = blockIdx.x, b = blockIdx.y, sp = blockIdx.z;
    __shared__ unsigned short ch[8 * SLOT8];   // 35840 B
    const int tid = threadIdx.x;
#pragma unroll
    for (int m = 0; m < 8; ++m) {
        const int j8 = 8 * g + m;
        if (j8 >= 28) break;
        const uint4* src = (const uint4*)(span8G + ((size_t)b * 28 + j8) * SLOT8);
        uint4* dst = (uint4*)(ch + m * SLOT8);
        for (int l = tid; l < SLOT8 / 8; l += 256) dst[l] = src[l];
    }
    __syncthreads();

    const int u0 = 64 * g;
    int ys8[8], nr8[8];
#pragma unroll
    for (int m = 0; m < 8; ++m) {
        const int um = u0 + 8 * m;
        if (um < 223) node_meta(um, min(8, 223 - um), ys8[m], nr8[m]);
        else { ys8[m] = 0; nr8[m] = 0; }
    }
    int ysO, nrO; node_meta(u0, min(64, 223 - u0), ysO, nrO);
    const int rpb = (nrO + 3) / 4;
    const int r0 = sp * rpb, r1 = min(nrO, r0 + rpb);
    const int cnt = (r1 - r0) * 224;
    if (cnt <= 0) return;
    unsigned short* R = span64G + ((size_t)b * 4 + g) * SLOT64 + r0 * 224;

    for (int pass = 0; pass < 2; ++pass) {
        const int ebase = pass * 2048;
        if (ebase >= cnt) break;
        unsigned q[8]; bool act[8];
#pragma unroll
        for (int t = 0; t < 8; ++t) {
            const int e = ebase + tid + t * 256;
            act[t] = e < cnt;
            const int ec = act[t] ? e : 0;
            const int pr = ysO + r0 + ec / 224, pc = ec - (ec / 224) * 224;
            q[t] = ((unsigned)pr << 8) | (unsigned)pc;
        }
#pragma unroll
        for (int m = 7; m >= 0; --m) {            // later nodes first
            const unsigned short* lb = ch + m * SLOT8;
#pragma unroll
            for (int t = 0; t < 8; ++t) {
                const unsigned qr = q[t] >> 8;
                const int qc = (int)(q[t] & 255u);
                const int off = (int)qr - ys8[m];
                const int offc = min(max(off, 0), 9);
                const unsigned rv = lb[__mul24(offc, 224) + qc];
                q[t] = ((unsigned)off < (unsigned)nr8[m]) ? rv : q[t];
            }
        }
#pragma unroll
        for (int t = 0; t < 8; ++t)
            if (act[t]) R[ebase + tid + t * 256] = (unsigned short)q[t];
    }
}

// ---------------- root4: 4 span-64 nodes -> P (4 hops, convert to 224-enc) ------------
// grid (64, 4), 512 threads, 118KB LDS.
__global__ __launch_bounds__(512) void root4_kernel(const unsigned short* __restrict__ span64G,
                                                    unsigned short* __restrict__ P) {
    const int b = blockIdx.x, sp = blockIdx.y;
    __shared__ unsigned short nd[4 * SLOT64];   // 118272 B
    const uint4* src = (const uint4*)(span64G + (size_t)b * 4 * SLOT64);
    for (int l = threadIdx.x; l < (4 * SLOT64) / 8; l += 512)
        ((uint4*)nd)[l] = src[l];
    __syncthreads();
    int ys[4], nr[4];
#pragma unroll
    for (int m = 0; m < 4; ++m) node_meta(64 * m, min(64, 223 - 64 * m), ys[m], nr[m]);
    unsigned short* Pb = P + (size_t)b * P_STRIDE;
    const int base0 = sp * 12544;
    for (int pass = 0; pass < 4; ++pass) {
        const int ebase = pass * 4096;
        if (ebase >= 12544) break;
        unsigned q[8]; bool act[8];
#pragma unroll
        for (int t = 0; t < 8; ++t) {
            const int e = ebase + (int)threadIdx.x + t * 512;
            act[t] = e < 12544;
            const int ec = act[t] ? (base0 + e) : 0;
            const int pr = ec / 224, pc = ec - pr * 224;
            q[t] = ((unsigned)pr << 8) | (unsigned)pc;
        }
#pragma unroll
        for (int m = 3; m >= 0; --m) {            // later groups first
            const unsigned short* lb = nd + m * SLOT64;
#pragma unroll
            for (int t = 0; t < 8; ++t) {
                const unsigned qr = q[t] >> 8;
                const int qc = (int)(q[t] & 255u);
                const int off = (int)qr - ys[m];
                const int offc = min(max(off, 0), 65);
                const unsigned rv = lb[__mul24(offc, 224) + qc];
                q[t] = ((unsigned)off < (unsigned)nr[m]) ? rv : q[t];
            }
        }
#pragma unroll
        for (int t = 0; t < 8; ++t)
            if (act[t])
                Pb[base0 + ebase + (int)threadIdx.x + t * 512] =
                    (unsigned short)(__mul24((int)(q[t] >> 8), 224) + (int)(q[t] & 255u));
    }
}

// ---------------- apply (fallback): plane(p) <- plane(P(p)), in-place via LDS ---------
__global__ __launch_bounds__(256) void apply_kernel(unsigned char* __restrict__ img,
                                                    const unsigned short* __restrict__ P) {
    const int plane = blockIdx.x;
    const int b = plane / 3;
    __shared__ __align__(16) unsigned char im[HH * WW];
    unsigned char* g = img + (size_t)plane * (HH * WW);
    for (int l = threadIdx.x; l < (HH * WW) / 16; l += 256)
        ((int4*)im)[l] = ((const int4*)g)[l];
    __syncthreads();
    const unsigned short* Pp = P + (size_t)b * P_STRIDE;
    for (int t = threadIdx.x; t < (HH * WW) / 8; t += 256) {
        uint4 pe = ((const uint4*)Pp)[t];
        unsigned e0 = pe.x & 0xffffu, e1 = pe.x >> 16;
        unsigned e2 = pe.y & 0xffffu, e3 = pe.y >> 16;
        unsigned e4 = pe.z & 0xffffu, e5 = pe.z >> 16;
        unsigned e6 = pe.w & 0xffffu, e7 = pe.w >> 16;
        unsigned lo = (unsigned)im[e0] | ((unsigned)im[e1] << 8)
                    | ((unsigned)im[e2] << 16) | ((unsigned)im[e3] << 24);
        unsigned hi = (unsigned)im[e4] | ((unsigned)im[e5] << 8)
                    | ((unsigned)im[e6] << 16) | ((unsigned)im[e7] << 24);
        ((uint2*)g)[t] = make_uint2(lo, hi);
    }
}

// ---------------- blur2 (plain, fallback) ----------------
__global__ __launch_bounds__(256) void blur2_kernel(const unsigned char* __restrict__ img,
                                                    float* __restrict__ out) {
    const int rb = blockIdx.x, c = blockIdx.y, b = blockIdx.z;
    const int y0 = rb * 8;
    __shared__ float A[12][WW];
    __shared__ float Bv[8][WW];
    const unsigned char* ip = img + ((size_t)(b * 3 + c)) * HH * WW;

    for (int l = threadIdx.x; l < 12 * WW; l += 256) {
        int r = l / WW, xx = l - r * WW;
        int gy = min(max(y0 + r - 2, 0), HH - 1);
        A[r][xx] = (float)ip[gy * WW + xx];
    }
    __syncthreads();
    for (int l = threadIdx.x; l < 8 * WW; l += 256) {
        int r = l / WW, xx = l - r * WW;
        Bv[r][xx] = KW2 * A[r][xx] + KW1 * A[r + 1][xx] + KW0 * A[r + 2][xx]
                  + KW1 * A[r + 3][xx] + KW2 * A[r + 4][xx];
    }
    __syncthreads();
    float* op = out + ((size_t)(b * 3 + c)) * HH * WW;
    for (int l = threadIdx.x; l < 8 * WW; l += 256) {
        int r = l / WW, xx = l - r * WW;
        int c0 = max(xx - 2, 0), c1 = max(xx - 1, 0);
        int c3 = min(xx + 1, WW - 1), c4 = min(xx + 2, WW - 1);
        float s = KW2 * Bv[r][c0] + KW1 * Bv[r][c1] + KW0 * Bv[r][xx]
                + KW1 * Bv[r][c3] + KW2 * Bv[r][c4];
        s = fminf(fmaxf(s, 0.0f), 255.0f);
        op[(y0 + r) * WW + xx] = floorf(s) / 255.0f;
    }
}

// ---------------- blur2_apply (fused): A[r][xx] = img[P[gy*224+xx]] ----------------
__global__ __launch_bounds__(256) void blur2_apply_kernel(const unsigned char* __restrict__ img,
                                                          const unsigned short* __restrict__ P,
                                                          float* __restrict__ out) {
    const int rb = blockIdx.x, c = blockIdx.y, b = blockIdx.z;
    const int y0 = rb * 8;
    __shared__ float A[12][WW];
    __shared__ float Bv[8][WW];
    const unsigned char* ip = img + ((size_t)(b * 3 + c)) * HH * WW;
    const unsigned short* Pp = P + (size_t)b * P_STRIDE;

    for (int l = threadIdx.x; l < 12 * WW; l += 256) {
        int r = l / WW, xx = l - r * WW;
        int gy = min(max(y0 + r - 2, 0), HH - 1);
        unsigned q = Pp[gy * WW + xx];
        A[r][xx] = (float)ip[q];
    }
    __syncthreads();
    for (int l = threadIdx.x; l < 8 * WW; l += 256) {
        int r = l / WW, xx = l - r * WW;
        Bv[r][xx] = KW2 * A[r][xx] + KW1 * A[r + 1][xx] + KW0 * A[r + 2][xx]
                  + KW1 * A[r + 3][xx] + KW2 * A[r + 4][xx];
    }
    __syncthreads();
    float* op = out + ((size_t)(b * 3 + c)) * HH * WW;
    for (int l = threadIdx.x; l < 8 * WW; l += 256) {
        int r = l / WW, xx = l - r * WW;
        int c0 = max(xx - 2, 0), c1 = max(xx - 1, 0);
        int c3 = min(xx + 1, WW - 1), c4 = min(xx + 2, WW - 1);
        float s = KW2 * Bv[r][c0] + KW1 * Bv[r][c1] + KW0 * Bv[r][xx]
                + KW1 * Bv[r][c3] + KW2 * Bv[r][c4];
        s = fminf(fmaxf(s, 0.0f), 255.0f);
        op[(y0 + r) * WW + xx] = floorf(s) / 255.0f;
    }
}

extern "C" void kernel_launch(void* const* d_in, const int* in_sizes, int n_in,
                              void* d_out, int out_size, void* d_ws, size_t ws_size,
                              hipStream_t stream) {
    const float* x      = (const float*)d_in[0];
    const int*   deltas = (const int*)d_in[1];
    float*       out    = (float*)d_out;
    unsigned char* img  = (unsigned char*)d_ws;                     // 9,633,792 B

    // scratch in d_out (u16 view) with lifetime overlap (d_out = 38.5 MB):
    //   leafG   [0 .. 19.38MB)      dead after chase8
    //   span8G  [19.38 .. 27.41MB)  dead after chase64
    //   span64G [0 .. 7.57MB)       reuses leafG region
    //   pFall   [7.57 .. 14.0MB)    reuses leafG region
    unsigned short* leafG   = (unsigned short*)d_out;               // 64*28*5408 u16
    unsigned short* span8G  = leafG + (size_t)64 * 28 * LEAF_GRP;   // 64*28*2240 u16
    unsigned short* span64G = (unsigned short*)d_out;               // 64*4*14784 u16
    unsigned short* pFall   = span64G + (size_t)64 * 4 * SLOT64;    // 64*50176 u16

    const bool fused = ws_size >= (size_t)9633792 + (size_t)64 * P_STRIDE * 2;
    unsigned short* P = fused ? (unsigned short*)(img + 9633792) : pFall;

    dim3 gb(28, 3, 64);
    blur1_kernel<<<gb, 256, 0, stream>>>(x, img);

    build_kernel<<<dim3(7, 64), 256, 0, stream>>>(deltas, leafG);
    chase8_kernel<<<dim3(28, 64), 256, 0, stream>>>(leafG, span8G);
    chase64_kernel<<<dim3(4, 64, 4), 256, 0, stream>>>(span8G, span64G);
    root4_kernel<<<dim3(64, 4), 512, 0, stream>>>(span64G, P);

    if (fused) {
        blur2_apply_kernel<<<gb, 256, 0, stream>>>(img, P, out);
    } else {
        apply_kernel<<<dim3(192), 256, 0, stream>>>(img, P);
        blur2_kernel<<<gb, 256, 0, stream>>>(img, out);
    }
}